// Round 6
// baseline (748.108 us; speedup 1.0000x reference)
//
#include <hip/hip_runtime.h>
#include <cstddef>
#include <cstdint>

// ---------------- problem constants ----------------
static constexpr int BN_   = 2;     // batch
static constexpr int L_    = 1024;  // sequence length (W/4)
static constexpr int DM_   = 512;   // d_model
static constexpr int EPROJ = 2192;  // in_proj out dim
static constexpr int DI_   = 1024;  // d_inner
static constexpr int CONVD = 1152;  // conv dim
static constexpr int HN_   = 16;    // heads
static constexpr int FH_   = 1024;  // ff hidden

// workspace float offsets
static constexpr size_t O_CONV1 = 0;                       // 2,097,152  (reused as y f32)
static constexpr size_t O_CONV2 = 2097152;                 // 1,048,576  (reused as proj)
static constexpr size_t O_TOKA  = O_CONV2 + 1048576;       // 1,048,576
static constexpr size_t O_TOKB  = O_TOKA + 1048576;        // 1,048,576
static constexpr size_t O_ZX    = O_TOKB + 1048576;        // 4,489,216  (tail reused as ffh_bf16)
static constexpr size_t O_XBC   = O_ZX + 4489216;          // 2,359,296  (reused as ffh f32)
static constexpr size_t O_DT    = O_XBC + 2359296;         // 32,768
static constexpr size_t O_DA    = O_DT + 32768;            // 32,768
static constexpr size_t O_FFO   = O_DA + 32768;            // 1,048,576 (scan Hbuf -> y_bf16 -> ffo)
static constexpr size_t O_STATS = O_FFO + 1048576;         // 16,672
static constexpr size_t STATS_SZ = 16672;
static constexpr size_t O_APROD = O_STATS + STATS_SZ;      // 256
static constexpr size_t O_WB    = O_APROD + 256;           // 14,336 floats (bf16 conv2 weights)
static constexpr size_t O_WBB   = O_WB + 14336;            // 2,695,168 floats (bf16 proj weights)
static constexpr size_t O_TABF  = O_WBB + 2695168;         // 524,288 (tokA bf16)
static constexpr size_t O_TBBF  = O_TABF + 524288;         // 524,288 (tokB bf16)

// bf16 weight segment offsets (in shorts)
static constexpr size_t WSEG_IN  = 0;         // 2,244,608
static constexpr size_t WSEG_OUT = 2244608;   // 1,048,576
static constexpr size_t WSEG_F1  = 3293184;   // 1,048,576
static constexpr size_t WSEG_F2  = 4341760;   // 1,048,576
static constexpr size_t WSEG_TOT = 5390336;

__device__ __forceinline__ float sigm(float x) { return 1.f / (1.f + expf(-x)); }

typedef __attribute__((ext_vector_type(8))) short short8;
typedef __attribute__((ext_vector_type(4))) float f32x4;

__device__ __forceinline__ ushort f2bf(float f) {
  union { float f; uint32_t u; } v; v.f = f;
  uint32_t u = v.u;
  uint32_t r = (u + 0x7fffu + ((u >> 16) & 1u)) >> 16;   // round-to-nearest-even
  return (ushort)r;
}
__device__ __forceinline__ uint32_t pk2(float a, float b) {
  return (uint32_t)f2bf(a) | ((uint32_t)f2bf(b) << 16);
}

// ---------------- conv stem ----------------
__global__ __launch_bounds__(256) void conv1_k(const float* __restrict__ img,
                                               const float* __restrict__ w,
                                               float* __restrict__ out) {
  int idx = blockIdx.x * 256 + threadIdx.x;               // 524288 threads, 4 outputs each
  int xq = idx & 511, y = (idx >> 9) & 31, c = (idx >> 14) & 15, b = idx >> 18;
  __shared__ float ws[49];
  if (threadIdx.x < 49) ws[threadIdx.x] = w[c * 49 + threadIdx.x];
  __syncthreads();
  int ix0 = 8 * xq - 3;
  bool fast = (xq > 0) && (xq < 511);
  float acc[4] = {0.f, 0.f, 0.f, 0.f};
  for (int ky = 0; ky < 7; ++ky) {
    int iy = 2 * y - 3 + ky;
    if ((unsigned)iy >= 64u) continue;
    const float* irow = img + ((size_t)b * 64 + iy) * 4096;
    float in[13];
    if (fast) {
      float4 f0 = *reinterpret_cast<const float4*>(&irow[ix0 - 1]);
      float4 f1 = *reinterpret_cast<const float4*>(&irow[ix0 + 3]);
      float4 f2 = *reinterpret_cast<const float4*>(&irow[ix0 + 7]);
      float4 f3 = *reinterpret_cast<const float4*>(&irow[ix0 + 11]);
      in[0] = f0.y; in[1] = f0.z; in[2] = f0.w;
      in[3] = f1.x; in[4] = f1.y; in[5] = f1.z; in[6] = f1.w;
      in[7] = f2.x; in[8] = f2.y; in[9] = f2.z; in[10] = f2.w;
      in[11] = f3.x; in[12] = f3.y;
    } else {
#pragma unroll
      for (int t = 0; t < 13; ++t) {
        int ix = ix0 + t;
        in[t] = ((unsigned)ix < 4096u) ? irow[ix] : 0.f;
      }
    }
#pragma unroll
    for (int kx = 0; kx < 7; ++kx) {
      float wv = ws[ky * 7 + kx];
#pragma unroll
      for (int j = 0; j < 4; ++j) acc[j] += in[2 * j + kx] * wv;
    }
  }
  float4 o; o.x = acc[0]; o.y = acc[1]; o.z = acc[2]; o.w = acc[3];
  *reinterpret_cast<float4*>(&out[(size_t)idx * 4]) = o;
}

// conv2 weight prep: w[32][16][7][7] f32 -> Wb[32][896] bf16, kx padded to 8
__global__ __launch_bounds__(256) void wprep_k(const float* __restrict__ w,
                                               ushort* __restrict__ wb) {
  int idx = blockIdx.x * 256 + threadIdx.x;   // 28672
  int c2 = idx / 896, r = idx % 896;
  int p = r >> 3, kx = r & 7;
  int c1 = p / 7, ky = p - c1 * 7;
  float v = (kx < 7) ? w[((size_t)(c2 * 16 + c1) * 7 + ky) * 7 + kx] : 0.f;
  wb[idx] = f2bf(v);
}

// cast all projection weights to bf16 (concatenated segments)
__global__ __launch_bounds__(256) void cast_w_k(const float* __restrict__ s0,
                                                const float* __restrict__ s1,
                                                const float* __restrict__ s2,
                                                const float* __restrict__ s3,
                                                ushort* __restrict__ d) {
  size_t base = ((size_t)blockIdx.x * 256 + threadIdx.x) * 8;
  if (base >= WSEG_TOT) return;
  const float* s; size_t off;
  if (base < WSEG_OUT)      { s = s0; off = base; }
  else if (base < WSEG_F1)  { s = s1; off = base - WSEG_OUT; }
  else if (base < WSEG_F2)  { s = s2; off = base - WSEG_F1; }
  else                      { s = s3; off = base - WSEG_F2; }
  float4 f0 = *reinterpret_cast<const float4*>(s + off);
  float4 f1 = *reinterpret_cast<const float4*>(s + off + 4);
  uint4 u;
  u.x = pk2(f0.x, f0.y); u.y = pk2(f0.z, f0.w);
  u.z = pk2(f1.x, f1.y); u.w = pk2(f1.z, f1.w);
  *reinterpret_cast<uint4*>(d + base) = u;
}

// conv2 as implicit-GEMM MFMA (bn1 fused into A-staging). grid 512.
__global__ __launch_bounds__(256) void conv2_mfma_k(const float* __restrict__ conv1out,
                                                    const float* __restrict__ bn1sums,
                                                    const float* __restrict__ bn1g,
                                                    const float* __restrict__ bn1b,
                                                    const ushort* __restrict__ Wb,
                                                    float* __restrict__ out) {
  constexpr int RS = 160;
  __shared__ ushort Asub[4 * RS];
  __shared__ ushort Bsub[32 * 40];
  __shared__ float s1l[16], t1l[16];
  int bid = blockIdx.x;
  int xt = bid & 15, y = (bid >> 4) & 15, b = bid >> 8;
  int x0 = xt * 64;
  int tid = threadIdx.x;
  int wave = tid >> 6, lane = tid & 63;
  int lr = lane >> 4, lc = lane & 15;
  int sr = wave, si = tid & 63;
  if (tid < 16) {
    float mean = bn1sums[tid] * (1.f / 131072.f);
    float var = bn1sums[16 + tid] * (1.f / 131072.f) - mean * mean;
    float s = bn1g[tid] * rsqrtf(var + 1e-5f);
    s1l[tid] = s; t1l[tid] = bn1b[tid] - mean * s;
  }
  f32x4 acc[2];
  acc[0] = (f32x4){0.f, 0.f, 0.f, 0.f};
  acc[1] = (f32x4){0.f, 0.f, 0.f, 0.f};
  __syncthreads();

  float aval[3];
  uint2 bval;
  auto fetch = [&](int c) {
    bval = *reinterpret_cast<const uint2*>(&Wb[(tid >> 3) * 896 + c * 32 + (tid & 7) * 4]);
    int p = 4 * c + sr;
    int c1 = p / 7, ky = p - c1 * 7;
    int iy = 2 * y - 3 + ky;
    bool rowok = (unsigned)iy < 32u;
    const float* src = conv1out + (((size_t)(b * 16 + c1) * 32 + (rowok ? iy : 0)) * 2048);
    float s1 = s1l[c1], t1v = t1l[c1];
#pragma unroll
    for (int rep = 0; rep < 3; ++rep) {
      int i = si + rep * 64;
      int gx = 2 * x0 + i - 3;
      bool ok = rowok && (i < 134) && ((unsigned)gx < 2048u);
      float raw = src[ok ? gx : 0];
      aval[rep] = ok ? (s1 * raw + t1v) : 0.f;
    }
  };

  fetch(0);
  for (int c = 0; c < 28; ++c) {
    *reinterpret_cast<uint2*>(&Bsub[(tid >> 3) * 40 + (tid & 7) * 4]) = bval;
#pragma unroll
    for (int rep = 0; rep < 3; ++rep) {
      int i = si + rep * 64;
      if (i < RS) Asub[sr * RS + i] = f2bf(aval[rep]);
    }
    __syncthreads();
    if (c + 1 < 28) fetch(c + 1);
    int pos = wave * 16 + lc;
    union { uint32_t u[4]; short8 s; } ua;
    ua.u[0] = *reinterpret_cast<const uint32_t*>(&Asub[lr * RS + 2 * pos + 0]);
    ua.u[1] = *reinterpret_cast<const uint32_t*>(&Asub[lr * RS + 2 * pos + 2]);
    ua.u[2] = *reinterpret_cast<const uint32_t*>(&Asub[lr * RS + 2 * pos + 4]);
    ua.u[3] = *reinterpret_cast<const uint32_t*>(&Asub[lr * RS + 2 * pos + 6]);
    short8 af = ua.s;
    short8 bf0 = *reinterpret_cast<const short8*>(&Bsub[(0 + lc) * 40 + lr * 8]);
    short8 bf1 = *reinterpret_cast<const short8*>(&Bsub[(16 + lc) * 40 + lr * 8]);
    acc[0] = __builtin_amdgcn_mfma_f32_16x16x32_bf16(af, bf0, acc[0], 0, 0, 0);
    acc[1] = __builtin_amdgcn_mfma_f32_16x16x32_bf16(af, bf1, acc[1], 0, 0, 0);
    __syncthreads();
  }
#pragma unroll
  for (int j = 0; j < 2; ++j) {
    int c2 = j * 16 + lc;
    size_t base = (((size_t)(b * 32 + c2)) * 16 + y) * 1024 + x0 + wave * 16 + lr * 4;
#pragma unroll
    for (int r = 0; r < 4; ++r) out[base + r] = acc[j][r];
  }
}

// per-channel stats for [B][C][S] tensor
__global__ __launch_bounds__(256) void stats_chan_k(const float* __restrict__ X,
                                                    float* __restrict__ sums,
                                                    int C, int S, int Bc) {
  int c = blockIdx.x, tid = threadIdx.x;
  float s = 0.f, q = 0.f;
  for (int b = 0; b < Bc; ++b) {
    const float* base = X + ((size_t)b * C + c) * S;
    for (int i = blockIdx.y * 256 + tid; i < S; i += gridDim.y * 256) {
      float v = base[i]; s += v; q += v * v;
    }
  }
  for (int o = 32; o > 0; o >>= 1) { s += __shfl_down(s, o); q += __shfl_down(q, o); }
  __shared__ float rs[4], rq[4];
  if ((tid & 63) == 0) { rs[tid >> 6] = s; rq[tid >> 6] = q; }
  __syncthreads();
  if (tid == 0) {
    atomicAdd(&sums[c], rs[0] + rs[1] + rs[2] + rs[3]);
    atomicAdd(&sums[C + c], rq[0] + rq[1] + rq[2] + rq[3]);
  }
}

__global__ __launch_bounds__(256) void img_stats_k(const float* __restrict__ img,
                                                   float* __restrict__ sums) {
  int idx = blockIdx.x * 256 + threadIdx.x;               // 32768 samples
  int xx = idx & 1023, yy = (idx >> 10) & 15, b = idx >> 14;
  float v = img[((size_t)b * 64 + yy * 4) * 4096 + xx * 4];
  float s = v, q = v * v;
  for (int o = 32; o > 0; o >>= 1) { s += __shfl_down(s, o); q += __shfl_down(q, o); }
  __shared__ float rs[4], rq[4];
  if ((threadIdx.x & 63) == 0) { rs[threadIdx.x >> 6] = s; rq[threadIdx.x >> 6] = q; }
  __syncthreads();
  if (threadIdx.x == 0) {
    atomicAdd(&sums[0], rs[0] + rs[1] + rs[2] + rs[3]);
    atomicAdd(&sums[1], rq[0] + rq[1] + rq[2] + rq[3]);
  }
}

// h = relu(bn2(conv2) + bn_ds(ds)); finalize fused; writes f32 + bf16 tokens
__global__ __launch_bounds__(256) void stem_fuse_k(const float* __restrict__ conv2,
                                                   const float* __restrict__ img,
                                                   const float* __restrict__ bn2sums,
                                                   const float* __restrict__ g2, const float* __restrict__ b2,
                                                   const float* __restrict__ imgsums,
                                                   const float* __restrict__ dsw,
                                                   const float* __restrict__ dsg, const float* __restrict__ dsb,
                                                   float* __restrict__ tok,
                                                   ushort* __restrict__ tok_bf) {
  int idx = blockIdx.x * 256 + threadIdx.x;               // 2*1024*512
  int d = idx & 511, l = (idx >> 9) & 1023, b = idx >> 19;
  int c = d >> 4, hh = d & 15;
  float m2 = bn2sums[c] * (1.f / 32768.f);
  float v2 = bn2sums[32 + c] * (1.f / 32768.f) - m2 * m2;
  float s2 = g2[c] * rsqrtf(v2 + 1e-5f);
  float mi = imgsums[0] * (1.f / 32768.f);
  float vi = imgsums[1] * (1.f / 32768.f) - mi * mi;
  float wv = dsw[c];
  float sd = dsg[c] * rsqrtf(wv * wv * vi + 1e-5f);
  float v = s2 * conv2[((size_t)(b * 32 + c) * 16 + hh) * 1024 + l] + (b2[c] - m2 * s2)
          + (wv * sd) * img[((size_t)b * 64 + hh * 4) * 4096 + l * 4] + (dsb[c] - wv * mi * sd);
  v = fmaxf(v, 0.f);
  tok[idx] = v;
  tok_bf[idx] = f2bf(v);
}

// -------- bf16 MFMA GEMM: Out(MxN f32) = A(MxK bf16) @ W(NxK bf16)^T (+bias) --------
// 2x2 waves, wave tile 16FM x 16FN, BK=64, double-buffered LDS with granule-XOR swizzle.
template <int BM, int BN, int FM, int FN>
__global__ __launch_bounds__(256) void gemm_bf_k(const ushort* __restrict__ A,
                                                 const ushort* __restrict__ W,
                                                 const float* __restrict__ bias,
                                                 float* __restrict__ Out,
                                                 float* __restrict__ colsums,
                                                 int M, int N, int K) {
  __shared__ ushort As[2][BM * 64];
  __shared__ ushort Bs[2][BN * 64];
  constexpr int TPA = 256 / BM, GPA = 8 / TPA;   // threads/row, granules(16B)/thread
  constexpr int TPB = 256 / BN, GPB = 8 / TPB;
  const int tid = threadIdx.x;
  const int bm = blockIdx.y * BM;
  const int bn = blockIdx.x * BN;
  const int wave = tid >> 6, lane = tid & 63;
  const int lr = lane >> 4, lc = lane & 15;
  const int wmo = (wave >> 1) * (FM * 16);
  const int wno = (wave & 1) * (FN * 16);

  const int arow = tid / TPA, aslot = tid % TPA;
  const int brow = tid / TPB, bslot = tid % TPB;
  const ushort* aptr = A + (size_t)(bm + arow) * K + aslot * (GPA * 8);
  const bool bok = (bn + brow) < N;
  const ushort* bptr = W + (size_t)(bok ? (bn + brow) : 0) * K + bslot * (GPB * 8);

  uint4 av[GPA], bv[GPB];
  f32x4 acc[FM][FN];
#pragma unroll
  for (int i = 0; i < FM; ++i)
#pragma unroll
    for (int j = 0; j < FN; ++j) acc[i][j] = (f32x4){0.f, 0.f, 0.f, 0.f};

  auto gload = [&](int k0) {
#pragma unroll
    for (int j = 0; j < GPA; ++j)
      av[j] = *reinterpret_cast<const uint4*>(aptr + k0 + j * 8);
#pragma unroll
    for (int j = 0; j < GPB; ++j)
      bv[j] = bok ? *reinterpret_cast<const uint4*>(bptr + k0 + j * 8)
                  : (uint4){0u, 0u, 0u, 0u};
  };
  auto lwrite = [&](int buf) {
#pragma unroll
    for (int j = 0; j < GPA; ++j) {
      int g = aslot * GPA + j;
      *reinterpret_cast<uint4*>(&As[buf][arow * 64 + ((g ^ (arow & 7)) * 8)]) = av[j];
    }
#pragma unroll
    for (int j = 0; j < GPB; ++j) {
      int g = bslot * GPB + j;
      *reinterpret_cast<uint4*>(&Bs[buf][brow * 64 + ((g ^ (brow & 7)) * 8)]) = bv[j];
    }
  };

  const int NT = K >> 6;
  gload(0);
  lwrite(0);
  __syncthreads();
  for (int t = 0; t < NT; ++t) {
    if (t + 1 < NT) gload((t + 1) << 6);       // issue early (latency hides under MFMA)
    const ushort* as = As[t & 1];
    const ushort* bs = Bs[t & 1];
#pragma unroll
    for (int ks = 0; ks < 2; ++ks) {
      short8 af[FM], bf[FN];
#pragma unroll
      for (int i = 0; i < FM; ++i) {
        int r = wmo + i * 16 + lc;
        af[i] = *reinterpret_cast<const short8*>(&as[r * 64 + (((ks * 4 + lr) ^ (r & 7)) * 8)]);
      }
#pragma unroll
      for (int j = 0; j < FN; ++j) {
        int r = wno + j * 16 + lc;
        bf[j] = *reinterpret_cast<const short8*>(&bs[r * 64 + (((ks * 4 + lr) ^ (r & 7)) * 8)]);
      }
#pragma unroll
      for (int i = 0; i < FM; ++i)
#pragma unroll
        for (int j = 0; j < FN; ++j)
          acc[i][j] = __builtin_amdgcn_mfma_f32_16x16x32_bf16(af[i], bf[j], acc[i][j], 0, 0, 0);
    }
    if (t + 1 < NT) lwrite((t + 1) & 1);       // write late (after compute)
    __syncthreads();
  }

#pragma unroll
  for (int j = 0; j < FN; ++j) {
    int gc = bn + wno + j * 16 + lc;
    if (gc >= N) continue;
    float bvv = bias ? bias[gc] : 0.f;
    float cs = 0.f, cq = 0.f;
#pragma unroll
    for (int i = 0; i < FM; ++i) {
      int gr = bm + wmo + i * 16 + lr * 4;
#pragma unroll
      for (int r = 0; r < 4; ++r) {
        float o = acc[i][j][r] + bvv;
        Out[(size_t)(gr + r) * N + gc] = o;
        cs += o; cq += o * o;
      }
    }
    if (colsums) {
      atomicAdd(&colsums[gc], cs);
      atomicAdd(&colsums[N + gc], cq);
    }
  }
}

// ---------------- mamba pieces ----------------
__global__ __launch_bounds__(256) void conv_silu_dt_k(const float* __restrict__ zx,
                                                      const float* __restrict__ cw,
                                                      const float* __restrict__ cb,
                                                      const float* __restrict__ dtb,
                                                      const float* __restrict__ alog,
                                                      float* __restrict__ out,
                                                      float* __restrict__ dtO,
                                                      float* __restrict__ dAO) {
  int idx = blockIdx.x * 256 + threadIdx.x;               // 2*1024*1152
  if (idx < 32768) {
    int h = idx & 15, row = idx >> 4;
    float raw = zx[(size_t)row * EPROJ + 2176 + h] + dtb[h];
    float dt = raw > 20.f ? raw : log1pf(expf(raw));
    dtO[idx] = dt;
    dAO[idx] = expf(dt * (-expf(alog[h])));
  }
  int c = idx % CONVD;
  int row = idx / CONVD;
  int l = row & 1023, bb = row >> 10;
  float acc = cb[c];
#pragma unroll
  for (int k = 0; k < 4; ++k) {
    int ll = l - 3 + k;
    if (ll >= 0) acc += zx[((size_t)(bb * 1024 + ll)) * EPROJ + 1024 + c] * cw[c * 4 + k];
  }
  out[idx] = acc * sigm(acc);
}

// -------- chunked selective scan --------
template <int EMITY>
__global__ __launch_bounds__(256) void scan_chunk_k(const float* __restrict__ xbc,
                                                    const float* __restrict__ dtA,
                                                    const float* __restrict__ dAA,
                                                    const float* __restrict__ Dq,
                                                    float* __restrict__ Hbuf,
                                                    float* __restrict__ aprod,
                                                    float* __restrict__ y) {
  constexpr int SCH = 16;
  int bid = blockIdx.x;
  int c  = bid & 7;
  int pg = (bid >> 3) & 3;
  int hh = (bid >> 5) & 15;
  int b  = bid >> 9;
  int tid = threadIdx.x;
  int pl = tid >> 4, nq = tid & 15, n0 = nq * 4;
  int p = pg * 16 + pl;
  __shared__ float sB[2][SCH][64], sC[2][SCH][64], sx[2][SCH][16];
  __shared__ float sdt[2][SCH], sdA[2][SCH];
  const float* xb = xbc + (size_t)b * L_ * CONVD;
  const float* dtp = dtA + b * (L_ * HN_) + hh;
  const float* dAp = dAA + b * (L_ * HN_) + hh;
  float* yp_ = y + (size_t)b * L_ * DI_ + hh * 64 + p;
  float Dh = Dq[hh];
  size_t hoff = (((size_t)c * 2 + b) * 16 + hh) * 4096 + (size_t)p * 64 + n0;

  float4 st = make_float4(0.f, 0.f, 0.f, 0.f);
  if (EMITY) st = *reinterpret_cast<const float4*>(&Hbuf[hoff]);
  float ap = 1.f;

  auto stage = [&](int l0, int buf) {
    int ll = tid >> 4, nn = (tid & 15) * 4;
    const float* base = xb + (size_t)(l0 + ll) * CONVD;
    *reinterpret_cast<float4*>(&sB[buf][ll][nn]) = *reinterpret_cast<const float4*>(base + 1024 + nn);
    if (EMITY)
      *reinterpret_cast<float4*>(&sC[buf][ll][nn]) = *reinterpret_cast<const float4*>(base + 1088 + nn);
    if (nq < 4) {
      *reinterpret_cast<float4*>(&sx[buf][ll][nq * 4]) =
          *reinterpret_cast<const float4*>(base + hh * 64 + pg * 16 + nq * 4);
    } else if (nq == 4) {
      sdt[buf][ll] = dtp[(l0 + ll) * HN_];
    } else if (nq == 5) {
      sdA[buf][ll] = dAp[(l0 + ll) * HN_];
    }
  };

  int lbase = c * 128;
  stage(lbase, 0);
  int buf = 0;
  for (int s = 0; s < 8; ++s) {
    __syncthreads();
    if (s + 1 < 8) stage(lbase + (s + 1) * SCH, buf ^ 1);
#pragma unroll
    for (int j = 0; j < SCH; ++j) {
      float xv = sx[buf][j][pl];
      float dtv = sdt[buf][j], dAv = sdA[buf][j];
      float4 Bv = *reinterpret_cast<float4*>(&sB[buf][j][n0]);
      float co = dtv * xv;
      st.x = dAv * st.x + co * Bv.x;
      st.y = dAv * st.y + co * Bv.y;
      st.z = dAv * st.z + co * Bv.z;
      st.w = dAv * st.w + co * Bv.w;
      if (EMITY) {
        float4 Cv = *reinterpret_cast<float4*>(&sC[buf][j][n0]);
        float yv = st.x * Cv.x + st.y * Cv.y + st.z * Cv.z + st.w * Cv.w;
        yv += __shfl_xor(yv, 1);
        yv += __shfl_xor(yv, 2);
        yv += __shfl_xor(yv, 4);
        yv += __shfl_xor(yv, 8);
        if (nq == 0) yp_[(size_t)(lbase + s * SCH + j) * DI_] = yv + Dh * xv;
      } else {
        ap *= dAv;
      }
    }
    buf ^= 1;
  }
  if (!EMITY) {
    *reinterpret_cast<float4*>(&Hbuf[hoff]) = st;
    if (tid == 0) aprod[c * 32 + b * 16 + hh] = ap;
  }
}

__global__ __launch_bounds__(256) void scan_comb_k(float* __restrict__ Hbuf,
                                                   const float* __restrict__ aprod) {
  int idx = blockIdx.x * 256 + threadIdx.x;               // 32768 = (b,h,p,n4)
  int n0 = (idx & 15) * 4;
  int p = (idx >> 4) & 63;
  int hh = (idx >> 10) & 15;
  int b = idx >> 14;
  size_t base = ((size_t)b * 16 + hh) * 4096 + (size_t)p * 64 + n0;
  float4 g = make_float4(0.f, 0.f, 0.f, 0.f);
#pragma unroll
  for (int c = 0; c < 8; ++c) {
    size_t off = (size_t)c * 131072 + base;
    float4 he = *reinterpret_cast<float4*>(&Hbuf[off]);
    float a = aprod[c * 32 + b * 16 + hh];
    *reinterpret_cast<float4*>(&Hbuf[off]) = g;
    g.x = a * g.x + he.x;
    g.y = a * g.y + he.y;
    g.z = a * g.z + he.z;
    g.w = a * g.w + he.w;
  }
}

// gated RMSNorm: reads y f32, writes bf16 (GEMM-ready)
__global__ __launch_bounds__(256) void rmsnorm_gate_k(const float* __restrict__ y,
                                                      const float* __restrict__ zx,
                                                      const float* __restrict__ nw,
                                                      ushort* __restrict__ out) {
  int row = blockIdx.x;
  const float* yr = y + (size_t)row * DI_;
  const float* zr = zx + (size_t)row * EPROJ;
  int d0 = threadIdx.x * 4;
  float4 yv = *reinterpret_cast<const float4*>(&yr[d0]);
  float4 zv = *reinterpret_cast<const float4*>(&zr[d0]);
  float4 g;
  g.x = yv.x * (zv.x * sigm(zv.x));
  g.y = yv.y * (zv.y * sigm(zv.y));
  g.z = yv.z * (zv.z * sigm(zv.z));
  g.w = yv.w * (zv.w * sigm(zv.w));
  float ss = g.x * g.x + g.y * g.y + g.z * g.z + g.w * g.w;
  for (int o = 32; o > 0; o >>= 1) ss += __shfl_down(ss, o);
  __shared__ float r4[4];
  __shared__ float tot;
  if ((threadIdx.x & 63) == 0) r4[threadIdx.x >> 6] = ss;
  __syncthreads();
  if (threadIdx.x == 0) tot = r4[0] + r4[1] + r4[2] + r4[3];
  __syncthreads();
  float rr = rsqrtf(tot * (1.f / DI_) + 1e-5f);
  float4 nwv = *reinterpret_cast<const float4*>(&nw[d0]);
  uint2 o2;
  o2.x = pk2(g.x * rr * nwv.x, g.y * rr * nwv.y);
  o2.y = pk2(g.z * rr * nwv.z, g.w * rr * nwv.w);
  *reinterpret_cast<uint2*>(&out[(size_t)row * DI_ + d0]) = o2;
}

// BN apply with finalize fused; optional f32 out, optional bf16 out
__global__ __launch_bounds__(256) void apply_bn_fin_k(const float* __restrict__ X,
                                                      const float* __restrict__ sums,
                                                      const float* __restrict__ g,
                                                      const float* __restrict__ bb,
                                                      const float* __restrict__ res,
                                                      float* __restrict__ out,
                                                      ushort* __restrict__ out_bf,
                                                      int cmask, int C, float inv, int relu) {
  int idx = blockIdx.x * 256 + threadIdx.x;
  int c = idx & cmask;
  float mean = sums[c] * inv;
  float var = sums[C + c] * inv - mean * mean;
  float s = g[c] * rsqrtf(var + 1e-5f);
  float v = s * X[idx] + (bb[c] - mean * s);
  if (res) v += res[idx];
  if (relu) v = fmaxf(v, 0.f);
  if (out) out[idx] = v;
  if (out_bf) out_bf[idx] = f2bf(v);
}

// LDS-tiled transpose: out[b][e][l] = tok[b][l][e]
__global__ __launch_bounds__(256) void transpose_k(const float* __restrict__ tok,
                                                   float* __restrict__ out) {
  __shared__ float tile[32][33];
  int bid = blockIdx.x;                                   // 1024 = 2b * 32lb * 16eb
  int eb = bid & 15, lb = (bid >> 4) & 31, b = bid >> 9;
  int tx = threadIdx.x & 31, ty = threadIdx.x >> 5;
#pragma unroll
  for (int i = 0; i < 4; ++i) {
    int l = lb * 32 + ty + i * 8;
    tile[ty + i * 8][tx] = tok[((size_t)b * 1024 + l) * 512 + eb * 32 + tx];
  }
  __syncthreads();
#pragma unroll
  for (int i = 0; i < 4; ++i) {
    int e = eb * 32 + ty + i * 8;
    out[((size_t)b * 512 + e) * 1024 + lb * 32 + tx] = tile[tx][ty + i * 8];
  }
}

// ---------------- launcher ----------------
extern "C" void kernel_launch(void* const* d_in, const int* in_sizes, int n_in,
                              void* d_out, int out_size, void* d_ws, size_t ws_size,
                              hipStream_t stream) {
  const float* img      = (const float*)d_in[0];
  const float* conv1_w  = (const float*)d_in[1];
  const float* bn1_g    = (const float*)d_in[2];
  const float* bn1_b    = (const float*)d_in[3];
  const float* conv2_w  = (const float*)d_in[4];
  const float* bn2_g    = (const float*)d_in[5];
  const float* bn2_b    = (const float*)d_in[6];
  const float* ds_w     = (const float*)d_in[7];
  const float* ds_g     = (const float*)d_in[8];
  const float* ds_b     = (const float*)d_in[9];
  const float* inproj_w = (const float*)d_in[10];
  const float* convw    = (const float*)d_in[11];
  const float* convb    = (const float*)d_in[12];
  const float* dt_bias  = (const float*)d_in[13];
  const float* A_log    = (const float*)d_in[14];
  const float* Dp       = (const float*)d_in[15];
  const float* norm_w   = (const float*)d_in[16];
  const float* outproj_w= (const float*)d_in[17];
  const float* bno_g    = (const float*)d_in[18];
  const float* bno_b    = (const float*)d_in[19];
  const float* ff_w1    = (const float*)d_in[20];
  const float* ff_b1    = (const float*)d_in[21];
  const float* ff1_g    = (const float*)d_in[22];
  const float* ff1_b    = (const float*)d_in[23];
  const float* ff_w2    = (const float*)d_in[24];
  const float* ff_b2    = (const float*)d_in[25];
  const float* ff2_g    = (const float*)d_in[26];
  const float* ff2_b    = (const float*)d_in[27];

  float* w = (float*)d_ws;
  float* stats = w + O_STATS;
  float* st_bn1 = stats + 0;     // 32
  float* st_bn2 = stats + 32;    // 64
  float* st_img = stats + 96;    // 2
  float* aprodp = w + O_APROD;
  ushort* wbp = (ushort*)(w + O_WB);
  ushort* WBB = (ushort*)(w + O_WBB);
  ushort* tokA_bf = (ushort*)(w + O_TABF);
  ushort* tokB_bf = (ushort*)(w + O_TBBF);
  ushort* ffh_bf  = (ushort*)(w + O_ZX);    // zx dead during FF phase
  ushort* y_bf    = (ushort*)(w + O_FFO);   // Hbuf dead after scan; ffo written later

  hipMemsetAsync(stats, 0, STATS_SZ * sizeof(float), stream);

  cast_w_k<<<2633, 256, 0, stream>>>(inproj_w, outproj_w, ff_w1, ff_w2, WBB);
  conv1_k<<<2048, 256, 0, stream>>>(img, conv1_w, w + O_CONV1);
  stats_chan_k<<<dim3(16, 8), 256, 0, stream>>>(w + O_CONV1, st_bn1, 16, 65536, 2);
  wprep_k<<<112, 256, 0, stream>>>(conv2_w, wbp);
  conv2_mfma_k<<<512, 256, 0, stream>>>(w + O_CONV1, st_bn1, bn1_g, bn1_b, wbp, w + O_CONV2);
  stats_chan_k<<<dim3(32, 8), 256, 0, stream>>>(w + O_CONV2, st_bn2, 32, 16384, 2);
  img_stats_k<<<128, 256, 0, stream>>>(img, st_img);
  stem_fuse_k<<<4096, 256, 0, stream>>>(w + O_CONV2, img, st_bn2, bn2_g, bn2_b,
                                        st_img, ds_w, ds_g, ds_b, w + O_TOKA, tokA_bf);

  float* tokA = w + O_TOKA;
  float* tokB = w + O_TOKB;
  float* zx   = w + O_ZX;
  float* xbc  = w + O_XBC;
  float* dtA  = w + O_DT;
  float* dAA  = w + O_DA;
  float* y    = w + O_CONV1;   // reuse
  float* proj = w + O_CONV2;   // reuse
  float* ffh  = w + O_XBC;     // reuse (xbc dead after scan)
  float* ffo  = w + O_FFO;     // after y_bf consumed
  float* Hbuf = w + O_FFO;

  for (int i = 0; i < 2; ++i) {
    float* stb = stats + 288 + i * 8192;
    const ushort* win_i  = WBB + WSEG_IN  + (size_t)i * 1122304;
    const ushort* wout_i = WBB + WSEG_OUT + (size_t)i * 524288;
    const ushort* wff1_i = WBB + WSEG_F1  + (size_t)i * 524288;
    const ushort* wff2_i = WBB + WSEG_F2  + (size_t)i * 524288;

    gemm_bf_k<64, 128, 2, 4><<<dim3(18, 32), 256, 0, stream>>>(
        tokA_bf, win_i, nullptr, zx, nullptr, 2048, EPROJ, DM_);
    conv_silu_dt_k<<<9216, 256, 0, stream>>>(zx, convw + i * CONVD * 4, convb + i * CONVD,
                                             dt_bias + i * 16, A_log + i * 16, xbc, dtA, dAA);
    scan_chunk_k<0><<<1024, 256, 0, stream>>>(xbc, dtA, dAA, Dp + i * 16, Hbuf, aprodp, y);
    scan_comb_k<<<128, 256, 0, stream>>>(Hbuf, aprodp);
    scan_chunk_k<1><<<1024, 256, 0, stream>>>(xbc, dtA, dAA, Dp + i * 16, Hbuf, aprodp, y);
    rmsnorm_gate_k<<<2048, 256, 0, stream>>>(y, zx, norm_w + i * DI_, y_bf);
    gemm_bf_k<64, 64, 2, 2><<<dim3(8, 32), 256, 0, stream>>>(
        y_bf, wout_i, nullptr, proj, stb, 2048, DM_, DI_);
    apply_bn_fin_k<<<4096, 256, 0, stream>>>(proj, stb, bno_g + i * DM_, bno_b + i * DM_,
                                             tokA, tokB, tokB_bf, DM_ - 1, DM_, 1.f / 2048.f, 0);
    gemm_bf_k<64, 128, 2, 4><<<dim3(8, 32), 256, 0, stream>>>(
        tokB_bf, wff1_i, ff_b1 + i * FH_, ffh, stb + 2048, 2048, FH_, DM_);
    apply_bn_fin_k<<<8192, 256, 0, stream>>>(ffh, stb + 2048, ff1_g + i * FH_, ff1_b + i * FH_,
                                             nullptr, nullptr, ffh_bf, FH_ - 1, FH_, 1.f / 2048.f, 1);
    gemm_bf_k<64, 64, 2, 2><<<dim3(8, 32), 256, 0, stream>>>(
        ffh_bf, wff2_i, ff_b2 + i * DM_, ffo, stb + 6144, 2048, DM_, FH_);
    apply_bn_fin_k<<<4096, 256, 0, stream>>>(ffo, stb + 6144, ff2_g + i * DM_, ff2_b + i * DM_,
                                             tokB, tokA, tokA_bf, DM_ - 1, DM_, 1.f / 2048.f, 0);
  }
  transpose_k<<<1024, 256, 0, stream>>>(tokA, (float*)d_out);
}

// Round 7
// 485.572 us; speedup vs baseline: 1.5407x; 1.5407x over previous
//
#include <hip/hip_runtime.h>
#include <cstddef>
#include <cstdint>

// ---------------- problem constants ----------------
static constexpr int L_    = 1024;
static constexpr int DM_   = 512;
static constexpr int EPROJ = 2192;
static constexpr int DI_   = 1024;
static constexpr int CONVD = 1152;
static constexpr int HN_   = 16;
static constexpr int FH_   = 1024;

// workspace float offsets (same envelope as round 6 — proven to fit)
static constexpr size_t O_CONV1 = 0;                       // 2,097,152 (conv1 -> y f32 -> ffh_bf/ffo_bf)
static constexpr size_t O_CONV2 = 2097152;                 // 1,048,576 (conv2 f32 -> y_bf)
static constexpr size_t O_TOKA  = O_CONV2 + 1048576;       // tokens A f32
static constexpr size_t O_TOKB  = O_TOKA + 1048576;        // tokens B f32
static constexpr size_t O_ZX    = O_TOKB + 1048576;        // 4,489,216 (zx bf16 -> proj bf16)
static constexpr size_t O_XBC   = O_ZX + 4489216;          // 2,359,296 xbc f32
static constexpr size_t O_DT    = O_XBC + 2359296;         // 32,768
static constexpr size_t O_DA    = O_DT + 32768;            // 32,768
static constexpr size_t O_FFO   = O_DA + 32768;            // 1,048,576 scan Hbuf
static constexpr size_t O_STATS = O_FFO + 1048576;         // 16,672
static constexpr size_t STATS_SZ = 16672;
static constexpr size_t O_APROD = O_STATS + STATS_SZ;      // 256
static constexpr size_t O_WB    = O_APROD + 256;           // 14,336 (conv2 w bf16)
static constexpr size_t O_WBB   = O_WB + 14336;            // 2,695,168 (proj weights bf16)
static constexpr size_t O_TABF  = O_WBB + 2695168;         // 524,288 tokA bf16
static constexpr size_t O_TBBF  = O_TABF + 524288;         // 524,288 tokB bf16

static constexpr size_t WSEG_IN  = 0;
static constexpr size_t WSEG_OUT = 2244608;
static constexpr size_t WSEG_F1  = 3293184;
static constexpr size_t WSEG_F2  = 4341760;
static constexpr size_t WSEG_TOT = 5390336;

__device__ __forceinline__ float sigm(float x) { return 1.f / (1.f + expf(-x)); }

typedef __attribute__((ext_vector_type(8))) short short8;
typedef __attribute__((ext_vector_type(4))) float f32x4;

__device__ __forceinline__ ushort f2bf(float f) {
  union { float f; uint32_t u; } v; v.f = f;
  uint32_t u = v.u;
  return (ushort)((u + 0x7fffu + ((u >> 16) & 1u)) >> 16);
}
__device__ __forceinline__ float bf2f(ushort u) {
  union { uint32_t u; float f; } v; v.u = (uint32_t)u << 16; return v.f;
}
__device__ __forceinline__ uint32_t pk2(float a, float b) {
  return (uint32_t)f2bf(a) | ((uint32_t)f2bf(b) << 16);
}
__device__ __forceinline__ void gl16(const ushort* g, ushort* l) {
  __builtin_amdgcn_global_load_lds(
      (const __attribute__((address_space(1))) void*)g,
      (__attribute__((address_space(3))) void*)l, 16, 0, 0);
}

// ---------------- prep: weight casts + img stats (merged) ----------------
__global__ __launch_bounds__(256) void prep_k(const float* __restrict__ s0, const float* __restrict__ s1,
                                              const float* __restrict__ s2, const float* __restrict__ s3,
                                              ushort* __restrict__ d,
                                              const float* __restrict__ c2w, ushort* __restrict__ wb,
                                              const float* __restrict__ img, float* __restrict__ imgsums) {
  int bx = blockIdx.x;
  if (bx < 2632) {                       // cast 4 proj-weight tensors to bf16
    size_t base = ((size_t)bx * 256 + threadIdx.x) * 8;
    const float* s; size_t off;
    if (base < WSEG_OUT)      { s = s0; off = base; }
    else if (base < WSEG_F1)  { s = s1; off = base - WSEG_OUT; }
    else if (base < WSEG_F2)  { s = s2; off = base - WSEG_F1; }
    else                      { s = s3; off = base - WSEG_F2; }
    float4 f0 = *reinterpret_cast<const float4*>(s + off);
    float4 f1 = *reinterpret_cast<const float4*>(s + off + 4);
    uint4 u;
    u.x = pk2(f0.x, f0.y); u.y = pk2(f0.z, f0.w);
    u.z = pk2(f1.x, f1.y); u.w = pk2(f1.z, f1.w);
    *reinterpret_cast<uint4*>(d + base) = u;
  } else if (bx < 2744) {                // conv2 weight prep (kx padded to 8)
    int idx = (bx - 2632) * 256 + threadIdx.x;
    int c2 = idx / 896, r = idx % 896;
    int p = r >> 3, kx = r & 7;
    int c1 = p / 7, ky = p - c1 * 7;
    float v = (kx < 7) ? c2w[((size_t)(c2 * 16 + c1) * 7 + ky) * 7 + kx] : 0.f;
    wb[idx] = f2bf(v);
  } else {                               // ds-path image stats (stride-4 samples)
    int idx = (bx - 2744) * 256 + threadIdx.x;
    int xx = idx & 1023, yy = (idx >> 10) & 15, b = idx >> 14;
    float v = img[((size_t)b * 64 + yy * 4) * 4096 + xx * 4];
    float s = v, q = v * v;
    for (int o = 32; o > 0; o >>= 1) { s += __shfl_down(s, o); q += __shfl_down(q, o); }
    __shared__ float rs[4], rq[4];
    if ((threadIdx.x & 63) == 0) { rs[threadIdx.x >> 6] = s; rq[threadIdx.x >> 6] = q; }
    __syncthreads();
    if (threadIdx.x == 0) {
      atomicAdd(&imgsums[0], rs[0] + rs[1] + rs[2] + rs[3]);
      atomicAdd(&imgsums[1], rq[0] + rq[1] + rq[2] + rq[3]);
    }
  }
}

// ---------------- conv stem ----------------
__global__ __launch_bounds__(256) void conv1_k(const float* __restrict__ img,
                                               const float* __restrict__ w,
                                               float* __restrict__ out,
                                               float* __restrict__ sums) {
  int idx = blockIdx.x * 256 + threadIdx.x;
  int xq = idx & 511, y = (idx >> 9) & 31, c = (idx >> 14) & 15, b = idx >> 18;
  __shared__ float ws[49];
  if (threadIdx.x < 49) ws[threadIdx.x] = w[c * 49 + threadIdx.x];
  __syncthreads();
  int ix0 = 8 * xq - 3;
  bool fast = (xq > 0) && (xq < 511);
  float acc[4] = {0.f, 0.f, 0.f, 0.f};
  for (int ky = 0; ky < 7; ++ky) {
    int iy = 2 * y - 3 + ky;
    if ((unsigned)iy >= 64u) continue;
    const float* irow = img + ((size_t)b * 64 + iy) * 4096;
    float in[13];
    if (fast) {
      float4 f0 = *reinterpret_cast<const float4*>(&irow[ix0 - 1]);
      float4 f1 = *reinterpret_cast<const float4*>(&irow[ix0 + 3]);
      float4 f2 = *reinterpret_cast<const float4*>(&irow[ix0 + 7]);
      float4 f3 = *reinterpret_cast<const float4*>(&irow[ix0 + 11]);
      in[0] = f0.y; in[1] = f0.z; in[2] = f0.w;
      in[3] = f1.x; in[4] = f1.y; in[5] = f1.z; in[6] = f1.w;
      in[7] = f2.x; in[8] = f2.y; in[9] = f2.z; in[10] = f2.w;
      in[11] = f3.x; in[12] = f3.y;
    } else {
#pragma unroll
      for (int t = 0; t < 13; ++t) {
        int ix = ix0 + t;
        in[t] = ((unsigned)ix < 4096u) ? irow[ix] : 0.f;
      }
    }
#pragma unroll
    for (int kx = 0; kx < 7; ++kx) {
      float wv = ws[ky * 7 + kx];
#pragma unroll
      for (int j = 0; j < 4; ++j) acc[j] += in[2 * j + kx] * wv;
    }
  }
  float4 o; o.x = acc[0]; o.y = acc[1]; o.z = acc[2]; o.w = acc[3];
  *reinterpret_cast<float4*>(&out[(size_t)idx * 4]) = o;
  // fused bn1 stats (c uniform across block)
  float s4 = acc[0] + acc[1] + acc[2] + acc[3];
  float q4 = acc[0]*acc[0] + acc[1]*acc[1] + acc[2]*acc[2] + acc[3]*acc[3];
  for (int o2 = 32; o2 > 0; o2 >>= 1) { s4 += __shfl_down(s4, o2); q4 += __shfl_down(q4, o2); }
  __shared__ float rs[4], rq[4];
  if ((threadIdx.x & 63) == 0) { rs[threadIdx.x >> 6] = s4; rq[threadIdx.x >> 6] = q4; }
  __syncthreads();
  if (threadIdx.x == 0) {
    atomicAdd(&sums[c], rs[0] + rs[1] + rs[2] + rs[3]);
    atomicAdd(&sums[16 + c], rq[0] + rq[1] + rq[2] + rq[3]);
  }
}

// conv2 implicit-GEMM MFMA; bn1 fused into A-staging; bn2 stats fused into epilogue.
__global__ __launch_bounds__(256) void conv2_mfma_k(const float* __restrict__ conv1out,
                                                    const float* __restrict__ bn1sums,
                                                    const float* __restrict__ bn1g,
                                                    const float* __restrict__ bn1b,
                                                    const ushort* __restrict__ Wb,
                                                    float* __restrict__ out,
                                                    float* __restrict__ bn2sums) {
  constexpr int RS = 160;
  __shared__ ushort Asub[4 * RS];
  __shared__ ushort Bsub[32 * 40];
  __shared__ float s1l[16], t1l[16];
  __shared__ float cred[64];
  int bid = blockIdx.x;
  int xt = bid & 15, y = (bid >> 4) & 15, b = bid >> 8;
  int x0 = xt * 64;
  int tid = threadIdx.x;
  int wave = tid >> 6, lane = tid & 63;
  int lr = lane >> 4, lc = lane & 15;
  int sr = wave, si = tid & 63;
  if (tid < 16) {
    float mean = bn1sums[tid] * (1.f / 131072.f);
    float var = bn1sums[16 + tid] * (1.f / 131072.f) - mean * mean;
    float s = bn1g[tid] * rsqrtf(var + 1e-5f);
    s1l[tid] = s; t1l[tid] = bn1b[tid] - mean * s;
  }
  if (tid < 64) cred[tid] = 0.f;
  f32x4 acc[2];
  acc[0] = (f32x4){0.f, 0.f, 0.f, 0.f};
  acc[1] = (f32x4){0.f, 0.f, 0.f, 0.f};
  __syncthreads();

  float aval[3];
  uint2 bval;
  auto fetch = [&](int c) {
    bval = *reinterpret_cast<const uint2*>(&Wb[(tid >> 3) * 896 + c * 32 + (tid & 7) * 4]);
    int p = 4 * c + sr;
    int c1 = p / 7, ky = p - c1 * 7;
    int iy = 2 * y - 3 + ky;
    bool rowok = (unsigned)iy < 32u;
    const float* src = conv1out + (((size_t)(b * 16 + c1) * 32 + (rowok ? iy : 0)) * 2048);
    float s1 = s1l[c1], t1v = t1l[c1];
#pragma unroll
    for (int rep = 0; rep < 3; ++rep) {
      int i = si + rep * 64;
      int gx = 2 * x0 + i - 3;
      bool ok = rowok && (i < 134) && ((unsigned)gx < 2048u);
      float raw = src[ok ? gx : 0];
      aval[rep] = ok ? (s1 * raw + t1v) : 0.f;
    }
  };

  fetch(0);
  for (int c = 0; c < 28; ++c) {
    *reinterpret_cast<uint2*>(&Bsub[(tid >> 3) * 40 + (tid & 7) * 4]) = bval;
#pragma unroll
    for (int rep = 0; rep < 3; ++rep) {
      int i = si + rep * 64;
      if (i < RS) Asub[sr * RS + i] = f2bf(aval[rep]);
    }
    __syncthreads();
    if (c + 1 < 28) fetch(c + 1);
    int pos = wave * 16 + lc;
    union { uint32_t u[4]; short8 s; } ua;
    ua.u[0] = *reinterpret_cast<const uint32_t*>(&Asub[lr * RS + 2 * pos + 0]);
    ua.u[1] = *reinterpret_cast<const uint32_t*>(&Asub[lr * RS + 2 * pos + 2]);
    ua.u[2] = *reinterpret_cast<const uint32_t*>(&Asub[lr * RS + 2 * pos + 4]);
    ua.u[3] = *reinterpret_cast<const uint32_t*>(&Asub[lr * RS + 2 * pos + 6]);
    short8 af = ua.s;
    short8 bf0 = *reinterpret_cast<const short8*>(&Bsub[(0 + lc) * 40 + lr * 8]);
    short8 bf1 = *reinterpret_cast<const short8*>(&Bsub[(16 + lc) * 40 + lr * 8]);
    acc[0] = __builtin_amdgcn_mfma_f32_16x16x32_bf16(af, bf0, acc[0], 0, 0, 0);
    acc[1] = __builtin_amdgcn_mfma_f32_16x16x32_bf16(af, bf1, acc[1], 0, 0, 0);
    __syncthreads();
  }
#pragma unroll
  for (int j = 0; j < 2; ++j) {
    int c2 = j * 16 + lc;
    size_t base = (((size_t)(b * 32 + c2)) * 16 + y) * 1024 + x0 + wave * 16 + lr * 4;
#pragma unroll
    for (int r = 0; r < 4; ++r) out[base + r] = acc[j][r];
  }
  // fused bn2 stats
#pragma unroll
  for (int j = 0; j < 2; ++j) {
    float cs = acc[j][0] + acc[j][1] + acc[j][2] + acc[j][3];
    float cq = acc[j][0]*acc[j][0] + acc[j][1]*acc[j][1] + acc[j][2]*acc[j][2] + acc[j][3]*acc[j][3];
    cs += __shfl_down(cs, 16); cs += __shfl_down(cs, 32);
    cq += __shfl_down(cq, 16); cq += __shfl_down(cq, 32);
    if (lane < 16) { atomicAdd(&cred[j * 16 + lane], cs); atomicAdd(&cred[32 + j * 16 + lane], cq); }
  }
  __syncthreads();
  if (tid < 64) atomicAdd(&bn2sums[tid], cred[tid]);
}

// h = relu(bn2(conv2) + bn_ds(ds)); writes f32 + bf16 tokens
__global__ __launch_bounds__(256) void stem_fuse_k(const float* __restrict__ conv2,
                                                   const float* __restrict__ img,
                                                   const float* __restrict__ bn2sums,
                                                   const float* __restrict__ g2, const float* __restrict__ b2,
                                                   const float* __restrict__ imgsums,
                                                   const float* __restrict__ dsw,
                                                   const float* __restrict__ dsg, const float* __restrict__ dsb,
                                                   float* __restrict__ tok,
                                                   ushort* __restrict__ tok_bf) {
  int idx = blockIdx.x * 256 + threadIdx.x;
  int d = idx & 511, l = (idx >> 9) & 1023, b = idx >> 19;
  int c = d >> 4, hh = d & 15;
  float m2 = bn2sums[c] * (1.f / 32768.f);
  float v2 = bn2sums[32 + c] * (1.f / 32768.f) - m2 * m2;
  float s2 = g2[c] * rsqrtf(v2 + 1e-5f);
  float mi = imgsums[0] * (1.f / 32768.f);
  float vi = imgsums[1] * (1.f / 32768.f) - mi * mi;
  float wv = dsw[c];
  float sd = dsg[c] * rsqrtf(wv * wv * vi + 1e-5f);
  float v = s2 * conv2[((size_t)(b * 32 + c) * 16 + hh) * 1024 + l] + (b2[c] - m2 * s2)
          + (wv * sd) * img[((size_t)b * 64 + hh * 4) * 4096 + l * 4] + (dsb[c] - wv * mi * sd);
  v = fmaxf(v, 0.f);
  tok[idx] = v;
  tok_bf[idx] = f2bf(v);
}

// -------- bf16 GEMM, m97-style: 64x64 tile, BK=64, global_load_lds, XCD swizzle --------
// Out bf16 = A(M x K bf16) @ W(N x K bf16)^T (+bias). Optional colsums; optional dt epilogue.
template <int DTEPI>
__global__ __launch_bounds__(256) void gemm64_k(const ushort* __restrict__ A,
                                                const ushort* __restrict__ W,
                                                const float* __restrict__ bias,
                                                ushort* __restrict__ Out,
                                                float* __restrict__ colsums,
                                                int N, int K,
                                                const float* __restrict__ dtb,
                                                const float* __restrict__ alog,
                                                float* __restrict__ dtO,
                                                float* __restrict__ dAO) {
  __shared__ ushort As[4096];
  __shared__ ushort Bs[4096];
  const int tid = threadIdx.x;
  const int GX = gridDim.x;
  int bid = blockIdx.y * GX + blockIdx.x;
  int xcd = bid & 7, slot = bid >> 3;            // bijective XCD-locality swizzle (GY=32 always)
  const int bm = (xcd * 4 + (slot & 3)) * 64;
  const int bn = (slot >> 2) * 64;
  const int wave = tid >> 6, lane = tid & 63;
  const int lr = lane >> 4, lc = lane & 15;
  const int wmo = (wave >> 1) * 32, wno = (wave & 1) * 32;

  // staging: chunk q = 16B granule; LDS linear, global source pre-XOR-swizzled (m173)
  const int q0 = (wave << 6) + lane, q1 = q0 + 256;
  const int r0 = q0 >> 3, g0 = q0 & 7;
  const int r1 = q1 >> 3, g1 = q1 & 7;
  const size_t ar0 = (size_t)(bm + r0) * K + ((g0 ^ (r0 & 7)) << 3);
  const size_t ar1 = (size_t)(bm + r1) * K + ((g1 ^ (r1 & 7)) << 3);
  int wr0 = bn + r0; wr0 = wr0 < N ? wr0 : N - 1;
  int wr1 = bn + r1; wr1 = wr1 < N ? wr1 : N - 1;
  const size_t br0 = (size_t)wr0 * K + ((g0 ^ (r0 & 7)) << 3);
  const size_t br1 = (size_t)wr1 * K + ((g1 ^ (r1 & 7)) << 3);
  ushort* la0 = &As[wave << 9];
  ushort* la1 = &As[2048 + (wave << 9)];
  ushort* lb0 = &Bs[wave << 9];
  ushort* lb1 = &Bs[2048 + (wave << 9)];

  f32x4 acc[2][2];
  acc[0][0] = acc[0][1] = acc[1][0] = acc[1][1] = (f32x4){0.f, 0.f, 0.f, 0.f};

  const int NT = K >> 6;
  for (int t = 0; t < NT; ++t) {
    const int k0 = t << 6;
    gl16(A + ar0 + k0, la0);
    gl16(A + ar1 + k0, la1);
    gl16(W + br0 + k0, lb0);
    gl16(W + br1 + k0, lb1);
    __syncthreads();                      // drains vmcnt -> loads landed
#pragma unroll
    for (int ks = 0; ks < 2; ++ks) {
      short8 af[2], bq[2];
#pragma unroll
      for (int i = 0; i < 2; ++i) {
        int row = wmo + i * 16 + lc;
        af[i] = *reinterpret_cast<const short8*>(&As[(row << 6) + ((((ks << 2) + lr) ^ (row & 7)) << 3)]);
      }
#pragma unroll
      for (int j = 0; j < 2; ++j) {
        int row = wno + j * 16 + lc;
        bq[j] = *reinterpret_cast<const short8*>(&Bs[(row << 6) + ((((ks << 2) + lr) ^ (row & 7)) << 3)]);
      }
#pragma unroll
      for (int i = 0; i < 2; ++i)
#pragma unroll
        for (int j = 0; j < 2; ++j)
          acc[i][j] = __builtin_amdgcn_mfma_f32_16x16x32_bf16(af[i], bq[j], acc[i][j], 0, 0, 0);
    }
    __syncthreads();                      // protect LDS overwrite by next tile
  }

  float bv[2];
#pragma unroll
  for (int j = 0; j < 2; ++j) {
    int gc = bn + wno + j * 16 + lc;
    bv[j] = (bias && gc < N) ? bias[gc] : 0.f;
  }
  if (colsums) {
#pragma unroll
    for (int j = 0; j < 2; ++j) {
      int gc = bn + wno + j * 16 + lc;
      float cs = 0.f, cq = 0.f;
#pragma unroll
      for (int i = 0; i < 2; ++i)
#pragma unroll
        for (int r = 0; r < 4; ++r) { float o = acc[i][j][r] + bv[j]; cs += o; cq += o * o; }
      cs += __shfl_down(cs, 16); cs += __shfl_down(cs, 32);
      cq += __shfl_down(cq, 16); cq += __shfl_down(cq, 32);
      if (lane < 16 && gc < N) { atomicAdd(&colsums[gc], cs); atomicAdd(&colsums[N + gc], cq); }
    }
  }
  if (DTEPI) {                            // dt softplus / dA from exact f32 acc
#pragma unroll
    for (int j = 0; j < 2; ++j) {
      int gc = bn + wno + j * 16 + lc;
      if (gc >= 2176 && gc < 2192) {
        int h = gc - 2176;
        float na = -expf(alog[h]);
        float db = dtb[h];
#pragma unroll
        for (int i = 0; i < 2; ++i)
#pragma unroll
          for (int r = 0; r < 4; ++r) {
            int row = bm + wmo + i * 16 + lr * 4 + r;
            float raw = acc[i][j][r] + db;
            float dt = raw > 20.f ? raw : log1pf(expf(raw));
            dtO[row * 16 + h] = dt;
            dAO[row * 16 + h] = expf(dt * na);
          }
      }
    }
  }
  // restage tile in LDS -> coalesced bf16 stores
#pragma unroll
  for (int i = 0; i < 2; ++i)
#pragma unroll
    for (int j = 0; j < 2; ++j)
#pragma unroll
      for (int r = 0; r < 4; ++r)
        As[((wmo + i * 16 + lr * 4 + r) << 6) + wno + j * 16 + lc] = f2bf(acc[i][j][r] + bv[j]);
  __syncthreads();
#pragma unroll
  for (int s = 0; s < 2; ++s) {
    int q = tid + s * 256;
    int r = q >> 3, g = q & 7;
    int col = bn + (g << 3);
    if (col < N)
      *reinterpret_cast<uint4*>(Out + (size_t)(bm + r) * N + col) =
          *reinterpret_cast<const uint4*>(&As[(r << 6) + (g << 3)]);
  }
}

// ---------------- mamba pieces ----------------
__global__ __launch_bounds__(256) void conv_silu_k(const ushort* __restrict__ zx,
                                                   const float* __restrict__ cw,
                                                   const float* __restrict__ cb,
                                                   float* __restrict__ out) {
  int idx = blockIdx.x * 256 + threadIdx.x;
  int c = idx % CONVD;
  int row = idx / CONVD;
  int l = row & 1023, bb = row >> 10;
  float acc = cb[c];
#pragma unroll
  for (int k = 0; k < 4; ++k) {
    int ll = l - 3 + k;
    if (ll >= 0) acc += bf2f(zx[((size_t)(bb * 1024 + ll)) * EPROJ + 1024 + c]) * cw[c * 4 + k];
  }
  out[idx] = acc * sigm(acc);
}

// scan phase A: local chunk states + dA products
__global__ __launch_bounds__(256) void scan_a_k(const float* __restrict__ xbc,
                                                const float* __restrict__ dtA,
                                                const float* __restrict__ dAA,
                                                float* __restrict__ Hbuf,
                                                float* __restrict__ aprod) {
  constexpr int SCH = 16;
  int bid = blockIdx.x;
  int c  = bid & 7;
  int pg = (bid >> 3) & 3;
  int hh = (bid >> 5) & 15;
  int b  = bid >> 9;
  int tid = threadIdx.x;
  int pl = tid >> 4, nq = tid & 15, n0 = nq * 4;
  int p = pg * 16 + pl;
  __shared__ float sB[2][SCH][64], sx[2][SCH][16];
  __shared__ float sdt[2][SCH], sdA[2][SCH];
  const float* xb = xbc + (size_t)b * L_ * CONVD;
  const float* dtp = dtA + b * (L_ * HN_) + hh;
  const float* dAp = dAA + b * (L_ * HN_) + hh;
  size_t hoff = (((size_t)c * 2 + b) * 16 + hh) * 4096 + (size_t)p * 64 + n0;
  float4 st = make_float4(0.f, 0.f, 0.f, 0.f);
  float ap = 1.f;
  auto stage = [&](int l0, int buf) {
    int ll = tid >> 4, nn = (tid & 15) * 4;
    const float* base = xb + (size_t)(l0 + ll) * CONVD;
    *reinterpret_cast<float4*>(&sB[buf][ll][nn]) = *reinterpret_cast<const float4*>(base + 1024 + nn);
    if (nq < 4)
      *reinterpret_cast<float4*>(&sx[buf][ll][nq * 4]) =
          *reinterpret_cast<const float4*>(base + hh * 64 + pg * 16 + nq * 4);
    else if (nq == 4) sdt[buf][ll] = dtp[(l0 + ll) * HN_];
    else if (nq == 5) sdA[buf][ll] = dAp[(l0 + ll) * HN_];
  };
  int lbase = c * 128;
  stage(lbase, 0);
  int buf = 0;
  for (int s = 0; s < 8; ++s) {
    __syncthreads();
    if (s + 1 < 8) stage(lbase + (s + 1) * SCH, buf ^ 1);
#pragma unroll
    for (int j = 0; j < SCH; ++j) {
      float xv = sx[buf][j][pl];
      float dtv = sdt[buf][j], dAv = sdA[buf][j];
      float4 Bv = *reinterpret_cast<float4*>(&sB[buf][j][n0]);
      float co = dtv * xv;
      st.x = dAv * st.x + co * Bv.x;
      st.y = dAv * st.y + co * Bv.y;
      st.z = dAv * st.z + co * Bv.z;
      st.w = dAv * st.w + co * Bv.w;
      ap *= dAv;
    }
    buf ^= 1;
  }
  *reinterpret_cast<float4*>(&Hbuf[hoff]) = st;
  if (tid == 0) aprod[c * 32 + b * 16 + hh] = ap;
}

// scan phase C: inline combine of predecessor chunk states, emit y
__global__ __launch_bounds__(256) void scan_c_k(const float* __restrict__ xbc,
                                                const float* __restrict__ dtA,
                                                const float* __restrict__ dAA,
                                                const float* __restrict__ Dq,
                                                const float* __restrict__ Hbuf,
                                                const float* __restrict__ aprod,
                                                float* __restrict__ y) {
  constexpr int SCH = 16;
  int bid = blockIdx.x;
  int c  = bid & 7;
  int pg = (bid >> 3) & 3;
  int hh = (bid >> 5) & 15;
  int b  = bid >> 9;
  int tid = threadIdx.x;
  int pl = tid >> 4, nq = tid & 15, n0 = nq * 4;
  int p = pg * 16 + pl;
  __shared__ float sB[2][SCH][64], sC[2][SCH][64], sx[2][SCH][16];
  __shared__ float sdt[2][SCH], sdA[2][SCH];
  const float* xb = xbc + (size_t)b * L_ * CONVD;
  const float* dtp = dtA + b * (L_ * HN_) + hh;
  const float* dAp = dAA + b * (L_ * HN_) + hh;
  float* yp_ = y + (size_t)b * L_ * DI_ + hh * 64 + p;
  float Dh = Dq[hh];
  float4 st = make_float4(0.f, 0.f, 0.f, 0.f);
  for (int cc = 0; cc < c; ++cc) {        // inline scan-combine (was scan_comb_k)
    float4 he = *reinterpret_cast<const float4*>(
        &Hbuf[(((size_t)cc * 2 + b) * 16 + hh) * 4096 + (size_t)p * 64 + n0]);
    float a = aprod[cc * 32 + b * 16 + hh];
    st.x = a * st.x + he.x;
    st.y = a * st.y + he.y;
    st.z = a * st.z + he.z;
    st.w = a * st.w + he.w;
  }
  auto stage = [&](int l0, int buf) {
    int ll = tid >> 4, nn = (tid & 15) * 4;
    const float* base = xb + (size_t)(l0 + ll) * CONVD;
    *reinterpret_cast<float4*>(&sB[buf][ll][nn]) = *reinterpret_cast<const float4*>(base + 1024 + nn);
    *reinterpret_cast<float4*>(&sC[buf][ll][nn]) = *reinterpret_cast<const float4*>(base + 1088 + nn);
    if (nq < 4)
      *reinterpret_cast<float4*>(&sx[buf][ll][nq * 4]) =
          *reinterpret_cast<const float4*>(base + hh * 64 + pg * 16 + nq * 4);
    else if (nq == 4) sdt[buf][ll] = dtp[(l0 + ll) * HN_];
    else if (nq == 5) sdA[buf][ll] = dAp[(l0 + ll) * HN_];
  };
  int lbase = c * 128;
  stage(lbase, 0);
  int buf = 0;
  for (int s = 0; s < 8; ++s) {
    __syncthreads();
    if (s + 1 < 8) stage(lbase + (s + 1) * SCH, buf ^ 1);
#pragma unroll
    for (int j = 0; j < SCH; ++j) {
      float xv = sx[buf][j][pl];
      float dtv = sdt[buf][j], dAv = sdA[buf][j];
      float4 Bv = *reinterpret_cast<float4*>(&sB[buf][j][n0]);
      float co = dtv * xv;
      st.x = dAv * st.x + co * Bv.x;
      st.y = dAv * st.y + co * Bv.y;
      st.z = dAv * st.z + co * Bv.z;
      st.w = dAv * st.w + co * Bv.w;
      float4 Cv = *reinterpret_cast<float4*>(&sC[buf][j][n0]);
      float yv = st.x * Cv.x + st.y * Cv.y + st.z * Cv.z + st.w * Cv.w;
      yv += __shfl_xor(yv, 1);
      yv += __shfl_xor(yv, 2);
      yv += __shfl_xor(yv, 4);
      yv += __shfl_xor(yv, 8);
      if (nq == 0) yp_[(size_t)(lbase + s * SCH + j) * DI_] = yv + Dh * xv;
    }
    buf ^= 1;
  }
}

// gated RMSNorm: y f32 + z (bf16 cols of zx) -> bf16
__global__ __launch_bounds__(256) void rmsnorm_gate_k(const float* __restrict__ y,
                                                      const ushort* __restrict__ zx,
                                                      const float* __restrict__ nw,
                                                      ushort* __restrict__ out) {
  int row = blockIdx.x;
  const float* yr = y + (size_t)row * DI_;
  const ushort* zr = zx + (size_t)row * EPROJ;
  int d0 = threadIdx.x * 4;
  float4 yv = *reinterpret_cast<const float4*>(&yr[d0]);
  ushort4 zu = *reinterpret_cast<const ushort4*>(&zr[d0]);
  float4 g;
  float z0 = bf2f(zu.x), z1 = bf2f(zu.y), z2 = bf2f(zu.z), z3 = bf2f(zu.w);
  g.x = yv.x * (z0 * sigm(z0));
  g.y = yv.y * (z1 * sigm(z1));
  g.z = yv.z * (z2 * sigm(z2));
  g.w = yv.w * (z3 * sigm(z3));
  float ss = g.x * g.x + g.y * g.y + g.z * g.z + g.w * g.w;
  for (int o = 32; o > 0; o >>= 1) ss += __shfl_down(ss, o);
  __shared__ float r4[4];
  __shared__ float tot;
  if ((threadIdx.x & 63) == 0) r4[threadIdx.x >> 6] = ss;
  __syncthreads();
  if (threadIdx.x == 0) tot = r4[0] + r4[1] + r4[2] + r4[3];
  __syncthreads();
  float rr = rsqrtf(tot * (1.f / DI_) + 1e-5f);
  float4 nwv = *reinterpret_cast<const float4*>(&nw[d0]);
  uint2 o2;
  o2.x = pk2(g.x * rr * nwv.x, g.y * rr * nwv.y);
  o2.y = pk2(g.z * rr * nwv.z, g.w * rr * nwv.w);
  *reinterpret_cast<uint2*>(&out[(size_t)row * DI_ + d0]) = o2;
}

// BN apply with finalize fused; X bf16; optional f32/bf16 outs; optional residual
__global__ __launch_bounds__(256) void apply_bn_fin_k(const ushort* __restrict__ X,
                                                      const float* __restrict__ sums,
                                                      const float* __restrict__ g,
                                                      const float* __restrict__ bb,
                                                      const float* __restrict__ res,
                                                      float* __restrict__ out,
                                                      ushort* __restrict__ out_bf,
                                                      int cmask, int C, float inv, int relu) {
  int idx = blockIdx.x * 256 + threadIdx.x;
  int c = idx & cmask;
  float mean = sums[c] * inv;
  float var = sums[C + c] * inv - mean * mean;
  float s = g[c] * rsqrtf(var + 1e-5f);
  float v = s * bf2f(X[idx]) + (bb[c] - mean * s);
  if (res) v += res[idx];
  if (relu) v = fmaxf(v, 0.f);
  if (out) out[idx] = v;
  if (out_bf) out_bf[idx] = f2bf(v);
}

// final BN + residual fused into LDS-tiled transpose: out[b][e][l]
__global__ __launch_bounds__(256) void transpose_bn_k(const ushort* __restrict__ ffo,
                                                      const float* __restrict__ sums,
                                                      const float* __restrict__ g,
                                                      const float* __restrict__ bb,
                                                      const float* __restrict__ res,
                                                      float* __restrict__ out) {
  __shared__ float tile[32][33];
  int bid = blockIdx.x;
  int eb = bid & 15, lb = (bid >> 4) & 31, b = bid >> 9;
  int tx = threadIdx.x & 31, ty = threadIdx.x >> 5;
  int e = eb * 32 + tx;
  float mean = sums[e] * (1.f / 2048.f);
  float var = sums[512 + e] * (1.f / 2048.f) - mean * mean;
  float s = g[e] * rsqrtf(var + 1e-5f);
  float t0 = bb[e] - mean * s;
#pragma unroll
  for (int i = 0; i < 4; ++i) {
    int l = lb * 32 + ty + i * 8;
    size_t off = ((size_t)b * 1024 + l) * 512 + e;
    tile[ty + i * 8][tx] = s * bf2f(ffo[off]) + t0 + res[off];
  }
  __syncthreads();
#pragma unroll
  for (int i = 0; i < 4; ++i) {
    int e2 = eb * 32 + ty + i * 8;
    out[((size_t)b * 512 + e2) * 1024 + lb * 32 + tx] = tile[tx][ty + i * 8];
  }
}

// ---------------- launcher ----------------
extern "C" void kernel_launch(void* const* d_in, const int* in_sizes, int n_in,
                              void* d_out, int out_size, void* d_ws, size_t ws_size,
                              hipStream_t stream) {
  const float* img      = (const float*)d_in[0];
  const float* conv1_w  = (const float*)d_in[1];
  const float* bn1_g    = (const float*)d_in[2];
  const float* bn1_b    = (const float*)d_in[3];
  const float* conv2_w  = (const float*)d_in[4];
  const float* bn2_g    = (const float*)d_in[5];
  const float* bn2_b    = (const float*)d_in[6];
  const float* ds_w     = (const float*)d_in[7];
  const float* ds_g     = (const float*)d_in[8];
  const float* ds_b     = (const float*)d_in[9];
  const float* inproj_w = (const float*)d_in[10];
  const float* convw    = (const float*)d_in[11];
  const float* convb    = (const float*)d_in[12];
  const float* dt_bias  = (const float*)d_in[13];
  const float* A_log    = (const float*)d_in[14];
  const float* Dp       = (const float*)d_in[15];
  const float* norm_w   = (const float*)d_in[16];
  const float* outproj_w= (const float*)d_in[17];
  const float* bno_g    = (const float*)d_in[18];
  const float* bno_b    = (const float*)d_in[19];
  const float* ff_w1    = (const float*)d_in[20];
  const float* ff_b1    = (const float*)d_in[21];
  const float* ff1_g    = (const float*)d_in[22];
  const float* ff1_b    = (const float*)d_in[23];
  const float* ff_w2    = (const float*)d_in[24];
  const float* ff_b2    = (const float*)d_in[25];
  const float* ff2_g    = (const float*)d_in[26];
  const float* ff2_b    = (const float*)d_in[27];

  float* w = (float*)d_ws;
  float* stats = w + O_STATS;
  float* st_bn1 = stats + 0;     // 32
  float* st_bn2 = stats + 32;    // 64
  float* st_img = stats + 96;    // 2
  float* aprodp = w + O_APROD;
  ushort* wbp = (ushort*)(w + O_WB);
  ushort* WBB = (ushort*)(w + O_WBB);

  float* tokA = w + O_TOKA;
  float* tokB = w + O_TOKB;
  ushort* tokA_bf = (ushort*)(w + O_TABF);
  ushort* tokB_bf = (ushort*)(w + O_TBBF);
  ushort* zx_bf   = (ushort*)(w + O_ZX);
  float* xbc  = w + O_XBC;
  float* dtA  = w + O_DT;
  float* dAA  = w + O_DA;
  float* Hbuf = w + O_FFO;
  float* y    = w + O_CONV1;                       // conv1out dead after conv2
  ushort* y_bf    = (ushort*)(w + O_CONV2);        // conv2 f32 dead after stem_fuse
  ushort* proj_bf = (ushort*)(w + O_ZX);           // zx dead after rms
  ushort* ffh_bf  = (ushort*)(w + O_CONV1);        // y dead after rms
  ushort* ffo_bf  = (ushort*)(w + O_CONV1 + 1048576);

  hipMemsetAsync(stats, 0, STATS_SZ * sizeof(float), stream);

  prep_k<<<2872, 256, 0, stream>>>(inproj_w, outproj_w, ff_w1, ff_w2, WBB,
                                   conv2_w, wbp, img, st_img);
  conv1_k<<<2048, 256, 0, stream>>>(img, conv1_w, w + O_CONV1, st_bn1);
  conv2_mfma_k<<<512, 256, 0, stream>>>(w + O_CONV1, st_bn1, bn1_g, bn1_b, wbp,
                                        w + O_CONV2, st_bn2);
  stem_fuse_k<<<4096, 256, 0, stream>>>(w + O_CONV2, img, st_bn2, bn2_g, bn2_b,
                                        st_img, ds_w, ds_g, ds_b, tokA, tokA_bf);

  for (int i = 0; i < 2; ++i) {
    float* stb = stats + 288 + i * 8192;
    const ushort* win_i  = WBB + WSEG_IN  + (size_t)i * 1122304;
    const ushort* wout_i = WBB + WSEG_OUT + (size_t)i * 524288;
    const ushort* wff1_i = WBB + WSEG_F1  + (size_t)i * 524288;
    const ushort* wff2_i = WBB + WSEG_F2  + (size_t)i * 524288;

    gemm64_k<1><<<dim3(35, 32), 256, 0, stream>>>(
        tokA_bf, win_i, nullptr, zx_bf, nullptr, EPROJ, DM_,
        dt_bias + i * 16, A_log + i * 16, dtA, dAA);
    conv_silu_k<<<9216, 256, 0, stream>>>(zx_bf, convw + i * CONVD * 4, convb + i * CONVD, xbc);
    scan_a_k<<<1024, 256, 0, stream>>>(xbc, dtA, dAA, Hbuf, aprodp);
    scan_c_k<<<1024, 256, 0, stream>>>(xbc, dtA, dAA, Dp + i * 16, Hbuf, aprodp, y);
    rmsnorm_gate_k<<<2048, 256, 0, stream>>>(y, zx_bf, norm_w + i * DI_, y_bf);
    gemm64_k<0><<<dim3(8, 32), 256, 0, stream>>>(
        y_bf, wout_i, nullptr, proj_bf, stb, DM_, DI_,
        nullptr, nullptr, nullptr, nullptr);
    apply_bn_fin_k<<<4096, 256, 0, stream>>>(proj_bf, stb, bno_g + i * DM_, bno_b + i * DM_,
                                             tokA, tokB, tokB_bf, DM_ - 1, DM_, 1.f / 2048.f, 0);
    gemm64_k<0><<<dim3(16, 32), 256, 0, stream>>>(
        tokB_bf, wff1_i, ff_b1 + i * FH_, ffh_bf, stb + 2048, FH_, DM_,
        nullptr, nullptr, nullptr, nullptr);
    apply_bn_fin_k<<<8192, 256, 0, stream>>>(ffh_bf, stb + 2048, ff1_g + i * FH_, ff1_b + i * FH_,
                                             nullptr, nullptr, ffh_bf, FH_ - 1, FH_, 1.f / 2048.f, 1);
    gemm64_k<0><<<dim3(8, 32), 256, 0, stream>>>(
        ffh_bf, wff2_i, ff_b2 + i * DM_, ffo_bf, stb + 6144, DM_, FH_,
        nullptr, nullptr, nullptr, nullptr);
    if (i == 0)
      apply_bn_fin_k<<<4096, 256, 0, stream>>>(ffo_bf, stb + 6144, ff2_g, ff2_b,
                                               tokB, tokA, tokA_bf, DM_ - 1, DM_, 1.f / 2048.f, 0);
  }
  transpose_bn_k<<<1024, 256, 0, stream>>>(ffo_bf, stats + 288 + 8192 + 6144,
                                           ff2_g + DM_, ff2_b + DM_, tokB, (float*)d_out);
}